// Round 3
// baseline (243.381 us; speedup 1.0000x reference)
//
#include <hip/hip_runtime.h>
#include <math.h>

// Problem constants (from reference): L=28, B=3, H=8, S=2048, D=128, V=152064
#define LAY 28
#define BEAM 3
#define NH 8
#define SEQ 2048
#define HD 128
#define VOCAB 152064
#define NBLK 32                 // blocks per logits row
#define NBLOCKS (BEAM * NBLK)   // 96
#define CHUNK (VOCAB / NBLK)    // 4752 (exact), = 1188 float4
#define CHUNK4 (CHUNK / 4)

static_assert(VOCAB % NBLK == 0, "chunking must be exact");
static_assert(CHUNK % 4 == 0, "chunk must be float4-divisible");

typedef float f32x4 __attribute__((ext_vector_type(4)));

// Per-(row,block) partial: online-LSE state + stable top-3. 10 words.
struct Partial {
    float m, s;
    float v[3];
    int   idx[3];
    int   pad[2];   // pad to 40->48 B not needed; keep 10 words via union below
};

#define PART_WORDS 10

__device__ __forceinline__ bool better(float a, int ai, float b, int bi) {
    // strict value order; ties broken by LOWER index (jax.lax.top_k semantics)
    return (a > b) || (a == b && ai < bi);
}

__device__ __forceinline__ void ins3(float x, int gi,
                                     float& v0, int& i0,
                                     float& v1, int& i1,
                                     float& v2, int& i2) {
    if (!better(x, gi, v2, i2)) return;
    if (better(x, gi, v0, i0)) { v2 = v1; i2 = i1; v1 = v0; i1 = i0; v0 = x; i0 = gi; }
    else if (better(x, gi, v1, i1)) { v2 = v1; i2 = i1; v1 = x; i1 = gi; }
    else { v2 = x; i2 = gi; }
}

// ---------------- fused pass A+B: per-chunk LSE/top-3, last block merges ----------------
// ws layout: [0..2] beam indices (int), [16] counter (int), [32...] partials (u32 words)
__global__ __launch_bounds__(256) void pass_ab(const float* __restrict__ logits,
                                               const int* __restrict__ save_id,
                                               const float* __restrict__ prev_prob,
                                               float* __restrict__ out_tail,  // d_out + OUT_KV
                                               int* __restrict__ beam_ws,
                                               unsigned* __restrict__ counter,
                                               unsigned* __restrict__ part_w, // NBLOCKS*PART_WORDS
                                               int hist) {
    __shared__ float sm[256], ss[256];
    __shared__ float sv[256][3];
    __shared__ int   sidx[256][3];
    __shared__ bool  is_last;

    const int row  = blockIdx.x / NBLK;
    const int blk  = blockIdx.x % NBLK;
    const int base = blk * CHUNK;
    const f32x4* p = (const f32x4*)(logits + (size_t)row * VOCAB + base);

    float m = -INFINITY, s = 0.f;
    float v0 = -INFINITY, v1 = -INFINITY, v2 = -INFINITY;
    int   i0 = 0x7fffffff, i1 = 0x7fffffff, i2 = 0x7fffffff;

    for (int i = threadIdx.x; i < CHUNK4; i += 256) {
        f32x4 x4 = p[i];
        #pragma unroll
        for (int k = 0; k < 4; ++k) {
            float x = x4[k];
            if (x > m) { s = s * expf(m - x) + 1.f; m = x; }
            else       { s += expf(x - m); }
            ins3(x, base + i * 4 + k, v0, i0, v1, i1, v2, i2);
        }
    }

    const int t = threadIdx.x;
    sm[t] = m; ss[t] = s;
    sv[t][0] = v0; sv[t][1] = v1; sv[t][2] = v2;
    sidx[t][0] = i0; sidx[t][1] = i1; sidx[t][2] = i2;
    __syncthreads();

    for (int w = 128; w >= 1; w >>= 1) {
        if (t < w) {
            float mo = sm[t + w], so = ss[t + w];
            float M  = fmaxf(m, mo);
            s = s * expf(m - M) + so * expf(mo - M);
            m = M;
            sm[t] = m; ss[t] = s;
            #pragma unroll
            for (int k = 0; k < 3; ++k)
                ins3(sv[t + w][k], sidx[t + w][k], v0, i0, v1, i1, v2, i2);
            sv[t][0] = v0; sv[t][1] = v1; sv[t][2] = v2;
            sidx[t][0] = i0; sidx[t][1] = i1; sidx[t][2] = i2;
        }
        __syncthreads();
    }

    // Publish this block's partial with agent-scope atomic stores, then count.
    if (t == 0) {
        unsigned* q = part_w + blockIdx.x * PART_WORDS;
        unsigned w_[PART_WORDS];
        w_[0] = __float_as_uint(m);  w_[1] = __float_as_uint(s);
        w_[2] = __float_as_uint(v0); w_[3] = __float_as_uint(v1); w_[4] = __float_as_uint(v2);
        w_[5] = (unsigned)i0; w_[6] = (unsigned)i1; w_[7] = (unsigned)i2;
        w_[8] = 0; w_[9] = 0;
        #pragma unroll
        for (int k = 0; k < PART_WORDS; ++k)
            __hip_atomic_store(&q[k], w_[k], __ATOMIC_RELAXED, __HIP_MEMORY_SCOPE_AGENT);
        unsigned old = __hip_atomic_fetch_add(counter, 1u, __ATOMIC_ACQ_REL,
                                              __HIP_MEMORY_SCOPE_AGENT);
        is_last = (old == NBLOCKS - 1);
    }
    __syncthreads();
    if (!is_last) return;

    // ---- last block: merge 32 partials per row (threads 0..2), then select ----
    __shared__ float lse_s[BEAM];
    __shared__ float fv_s[BEAM][3];
    __shared__ int   fi_s[BEAM][3];

    if (t < BEAM) {
        float mm = -INFINITY, sS = 0.f;
        float a0 = -INFINITY, a1 = -INFINITY, a2 = -INFINITY;
        int   b0 = 0x7fffffff, b1 = 0x7fffffff, b2 = 0x7fffffff;
        for (int b = 0; b < NBLK; ++b) {
            const unsigned* q = part_w + (t * NBLK + b) * PART_WORDS;
            unsigned w_[8];
            #pragma unroll
            for (int k = 0; k < 8; ++k)
                w_[k] = __hip_atomic_load(&q[k], __ATOMIC_RELAXED, __HIP_MEMORY_SCOPE_AGENT);
            float qm = __uint_as_float(w_[0]), qs = __uint_as_float(w_[1]);
            float M = fmaxf(mm, qm);
            sS = sS * expf(mm - M) + qs * expf(qm - M);
            mm = M;
            ins3(__uint_as_float(w_[2]), (int)w_[5], a0, b0, a1, b1, a2, b2);
            ins3(__uint_as_float(w_[3]), (int)w_[6], a0, b0, a1, b1, a2, b2);
            ins3(__uint_as_float(w_[4]), (int)w_[7], a0, b0, a1, b1, a2, b2);
        }
        lse_s[t] = mm + logf(sS);
        fv_s[t][0] = a0; fv_s[t][1] = a1; fv_s[t][2] = a2;
        fi_s[t][0] = b0; fi_s[t][1] = b1; fi_s[t][2] = b2;
    }
    __syncthreads();

    if (t == 0) {
        float cp[BEAM * 3];
        for (int r = 0; r < BEAM; ++r)
            for (int k = 0; k < 3; ++k)
                cp[r * 3 + k] = fv_s[r][k] - lse_s[r] + prev_prob[r];

        int  sel[3];
        bool used[BEAM * 3] = {false,false,false,false,false,false,false,false,false};
        for (int j = 0; j < 3; ++j) {
            int best = -1;
            for (int c = 0; c < BEAM * 3; ++c) {
                if (used[c]) continue;
                if (best < 0 || cp[c] > cp[best]) best = c;  // scan order => lowest idx wins ties
            }
            used[best] = true;
            sel[j] = best;
        }

        int tok0 = 0;
        for (int j = 0; j < 3; ++j) {
            const int beam = sel[j] / 3;
            const int tok  = fi_s[beam][sel[j] % 3];
            if (j == 0) tok0 = tok;
            beam_ws[j] = beam;
            out_tail[j] = (float)tok;                         // top_beam_indices [3,1]
            for (int h = 0; h < hist; ++h)                     // new_save_id [3, hist+1]
                out_tail[3 + j * (hist + 1) + h] = (float)save_id[beam * hist + h];
            out_tail[3 + j * (hist + 1) + hist] = (float)tok;
            out_tail[3 + 3 * (hist + 1) + j] = cp[sel[j]];     // top_beam_prob [3,1]
        }
        out_tail[3 + 3 * (hist + 1) + 3] = (float)tok0;        // max_logits_idx [1]
    }
}

// ---------------- KV gather-copy (the 1.4 GB mover) ----------------
// 4096 blocks x 256 threads = 2^20 threads; N4 = 42 * 2^20 exactly -> no bounds check.
__global__ __launch_bounds__(256) void copy_kv(const f32x4* __restrict__ src,
                                               const int* __restrict__ beam,
                                               f32x4* __restrict__ dst) {
    constexpr size_t CH4 = (size_t)NH * SEQ * HD / 4;   // 524288 = 2^19
    constexpr size_t N4  = (size_t)LAY * BEAM * CH4;    // 44,040,192 = 42 * 2^20
    static_assert(CH4 == ((size_t)1 << 19), "chunk must be 2^19 float4s");
    static_assert(N4 % ((size_t)4096 * 256) == 0, "grid must divide N4 exactly");

    // Pre-resolved source base pointer per output chunk (l, beam-slot)
    __shared__ const f32x4* sbase[LAY * BEAM];
    if (threadIdx.x < LAY * BEAM) {
        const int c  = threadIdx.x;
        const int l  = c / 3;
        const int bp = c - l * 3;
        sbase[c] = src + ((size_t)(l * 3 + beam[bp])) * CH4;
    }
    __syncthreads();

    const size_t stride = (size_t)4096 * 256;
    size_t i = (size_t)blockIdx.x * 256 + threadIdx.x;
    // 42 = 6 * 7: unroll 6 -> 6 loads then 6 NT stores per group, deeper MLP.
    #pragma unroll 6
    for (int it = 0; it < 42; ++it, i += stride) {
        const f32x4* sp = sbase[i >> 19];
        f32x4 v = sp[i & (CH4 - 1)];
        __builtin_nontemporal_store(v, &dst[i]);   // dst is never re-read: bypass cache
    }
}

extern "C" void kernel_launch(void* const* d_in, const int* in_sizes, int n_in,
                              void* d_out, int out_size, void* d_ws, size_t ws_size,
                              hipStream_t stream) {
    const float* kv        = (const float*)d_in[0];
    const float* logits    = (const float*)d_in[1];
    const int*   save_id   = (const int*)d_in[2];
    const float* prev_prob = (const float*)d_in[3];

    const int hist = in_sizes[2] / BEAM;   // 64
    const size_t OUT_KV = (size_t)LAY * BEAM * NH * SEQ * HD;  // 176,160,768

    float* out      = (float*)d_out;
    int*   beam_ws  = (int*)d_ws;                       // [0..2]
    unsigned* counter = (unsigned*)((char*)d_ws + 64);  // 1 word
    unsigned* part_w  = (unsigned*)((char*)d_ws + 128); // 96 * 10 words

    // Zero the arrival counter every call (ws is NOT re-poisoned between replays).
    hipMemsetAsync(counter, 0, sizeof(unsigned), stream);

    pass_ab<<<NBLOCKS, 256, 0, stream>>>(logits, save_id, prev_prob,
                                         out + OUT_KV, beam_ws, counter, part_w, hist);
    copy_kv<<<4096, 256, 0, stream>>>((const f32x4*)kv, beam_ws, (f32x4*)out);
}

// Round 4
// 237.437 us; speedup vs baseline: 1.0250x; 1.0250x over previous
//
#include <hip/hip_runtime.h>
#include <math.h>

// Problem constants (from reference): L=28, B=3, H=8, S=2048, D=128, V=152064
#define LAY 28
#define BEAM 3
#define NH 8
#define SEQ 2048
#define HD 128
#define VOCAB 152064
#define TOPK 3
#define NBLK 32                 // blocks per logits row in pass_a
#define CHUNK (VOCAB / NBLK)    // 4752 (exact), = 1188 float4
#define CHUNK4 (CHUNK / 4)

static_assert(VOCAB % NBLK == 0, "chunking must be exact");
static_assert(CHUNK % 4 == 0, "chunk must be float4-divisible");

typedef float f32x4 __attribute__((ext_vector_type(4)));

// Per-(row,block) partial: online-LSE state + stable top-3
struct Partial {
    float m, s;
    float v[3];
    int   idx[3];
};

__device__ __forceinline__ bool better(float a, int ai, float b, int bi) {
    // strict value order; ties broken by LOWER index (jax.lax.top_k semantics)
    return (a > b) || (a == b && ai < bi);
}

__device__ __forceinline__ void ins3(float x, int gi,
                                     float& v0, int& i0,
                                     float& v1, int& i1,
                                     float& v2, int& i2) {
    if (!better(x, gi, v2, i2)) return;
    if (better(x, gi, v0, i0)) { v2 = v1; i2 = i1; v1 = v0; i1 = i0; v0 = x; i0 = gi; }
    else if (better(x, gi, v1, i1)) { v2 = v1; i2 = i1; v1 = x; i1 = gi; }
    else { v2 = x; i2 = gi; }
}

// ---------------- pass A: per-chunk online LSE + top-3 (float4 loads) ----------------
__global__ __launch_bounds__(256) void pass_a(const float* __restrict__ logits,
                                              Partial* __restrict__ part) {
    __shared__ float sm[256], ss[256];
    __shared__ float sv[256][3];
    __shared__ int   sidx[256][3];

    const int row  = blockIdx.x / NBLK;
    const int blk  = blockIdx.x % NBLK;
    const int base = blk * CHUNK;
    const f32x4* p = (const f32x4*)(logits + (size_t)row * VOCAB + base);

    float m = -INFINITY, s = 0.f;
    float v0 = -INFINITY, v1 = -INFINITY, v2 = -INFINITY;
    int   i0 = 0x7fffffff, i1 = 0x7fffffff, i2 = 0x7fffffff;

    for (int i = threadIdx.x; i < CHUNK4; i += 256) {
        f32x4 x4 = p[i];
        #pragma unroll
        for (int k = 0; k < 4; ++k) {
            float x = x4[k];
            if (x > m) { s = s * expf(m - x) + 1.f; m = x; }
            else       { s += expf(x - m); }
            ins3(x, base + i * 4 + k, v0, i0, v1, i1, v2, i2);
        }
    }

    const int t = threadIdx.x;
    sm[t] = m; ss[t] = s;
    sv[t][0] = v0; sv[t][1] = v1; sv[t][2] = v2;
    sidx[t][0] = i0; sidx[t][1] = i1; sidx[t][2] = i2;
    __syncthreads();

    for (int w = 128; w >= 1; w >>= 1) {
        if (t < w) {
            float mo = sm[t + w], so = ss[t + w];
            float M  = fmaxf(m, mo);
            s = s * expf(m - M) + so * expf(mo - M);
            m = M;
            sm[t] = m; ss[t] = s;
            #pragma unroll
            for (int k = 0; k < 3; ++k)
                ins3(sv[t + w][k], sidx[t + w][k], v0, i0, v1, i1, v2, i2);
            sv[t][0] = v0; sv[t][1] = v1; sv[t][2] = v2;
            sidx[t][0] = i0; sidx[t][1] = i1; sidx[t][2] = i2;
        }
        __syncthreads();
    }

    if (t == 0) {
        Partial q;
        q.m = m; q.s = s;
        q.v[0] = v0; q.v[1] = v1; q.v[2] = v2;
        q.idx[0] = i0; q.idx[1] = i1; q.idx[2] = i2;
        part[blockIdx.x] = q;
    }
}

// ---------------- pass B: merge partials, beam selection, tail outputs ----------------
__global__ void pass_b(const Partial* __restrict__ part,
                       const int* __restrict__ save_id,
                       const float* __restrict__ prev_prob,
                       float* __restrict__ out_tail,   // d_out + OUT_KV
                       int* __restrict__ beam_ws,
                       int hist) {
    __shared__ float lse_s[BEAM];
    __shared__ float v_s[BEAM][3];
    __shared__ int   i_s[BEAM][3];

    const int t = threadIdx.x;
    if (t < BEAM) {
        float m = -INFINITY, s = 0.f;
        float v0 = -INFINITY, v1 = -INFINITY, v2 = -INFINITY;
        int   i0 = 0x7fffffff, i1 = 0x7fffffff, i2 = 0x7fffffff;
        for (int b = 0; b < NBLK; ++b) {
            Partial q = part[t * NBLK + b];
            float M = fmaxf(m, q.m);
            s = s * expf(m - M) + q.s * expf(q.m - M);
            m = M;
            #pragma unroll
            for (int k = 0; k < 3; ++k)
                ins3(q.v[k], q.idx[k], v0, i0, v1, i1, v2, i2);
        }
        lse_s[t] = m + logf(s);
        v_s[t][0] = v0; v_s[t][1] = v1; v_s[t][2] = v2;
        i_s[t][0] = i0; i_s[t][1] = i1; i_s[t][2] = i2;
    }
    __syncthreads();

    if (t == 0) {
        float cp[BEAM * 3];
        for (int r = 0; r < BEAM; ++r)
            for (int k = 0; k < 3; ++k)
                cp[r * 3 + k] = v_s[r][k] - lse_s[r] + prev_prob[r];

        int  sel[3];
        bool used[BEAM * 3] = {false, false, false, false, false, false, false, false, false};
        for (int j = 0; j < 3; ++j) {
            int best = -1;
            for (int c = 0; c < BEAM * 3; ++c) {
                if (used[c]) continue;
                if (best < 0 || cp[c] > cp[best]) best = c;  // scan order => lowest idx wins ties
            }
            used[best] = true;
            sel[j] = best;
        }

        int tok0 = 0;
        for (int j = 0; j < 3; ++j) {
            const int beam = sel[j] / 3;
            const int tok  = i_s[beam][sel[j] % 3];
            if (j == 0) tok0 = tok;
            beam_ws[j] = beam;
            // top_beam_indices [3,1]
            out_tail[j] = (float)tok;
            // new_save_id [3, hist+1]
            for (int h = 0; h < hist; ++h)
                out_tail[3 + j * (hist + 1) + h] = (float)save_id[beam * hist + h];
            out_tail[3 + j * (hist + 1) + hist] = (float)tok;
            // top_beam_prob [3,1]
            out_tail[3 + 3 * (hist + 1) + j] = cp[sel[j]];
        }
        // max_logits_idx [1]
        out_tail[3 + 3 * (hist + 1) + 3] = (float)tok0;
    }
}

// ---------------- pass C: KV gather-copy (the 1.4 GB mover) ----------------
// 4096 blocks x 256 threads = 2^20 threads; N4 = 42 * 2^20 exactly -> no bounds check.
__global__ __launch_bounds__(256) void copy_kv(const f32x4* __restrict__ src,
                                               const int* __restrict__ beam,
                                               f32x4* __restrict__ dst) {
    constexpr size_t CH4 = (size_t)NH * SEQ * HD / 4;   // 524288 = 2^19
    constexpr size_t N4  = (size_t)LAY * BEAM * CH4;    // 44,040,192 = 42 * 2^20
    static_assert(CH4 == ((size_t)1 << 19), "chunk must be 2^19 float4s");
    static_assert(N4 % ((size_t)4096 * 256) == 0, "grid must divide N4 exactly");

    // Pre-resolved source base pointer per output chunk (l, beam-slot)
    __shared__ const f32x4* sbase[LAY * BEAM];
    if (threadIdx.x < LAY * BEAM) {
        const int c  = threadIdx.x;
        const int l  = c / 3;
        const int bp = c - l * 3;
        sbase[c] = src + ((size_t)(l * 3 + beam[bp])) * CH4;
    }
    __syncthreads();

    const size_t stride = (size_t)4096 * 256;
    size_t i = (size_t)blockIdx.x * 256 + threadIdx.x;
    // 42 = 6 * 7: unroll 6 -> 6 loads then 6 NT stores per group, deeper MLP.
    #pragma unroll 6
    for (int it = 0; it < 42; ++it, i += stride) {
        const f32x4* sp = sbase[i >> 19];
        f32x4 v = sp[i & (CH4 - 1)];
        __builtin_nontemporal_store(v, &dst[i]);   // dst is never re-read: bypass cache
    }
}

extern "C" void kernel_launch(void* const* d_in, const int* in_sizes, int n_in,
                              void* d_out, int out_size, void* d_ws, size_t ws_size,
                              hipStream_t stream) {
    const float* kv        = (const float*)d_in[0];
    const float* logits    = (const float*)d_in[1];
    const int*   save_id   = (const int*)d_in[2];
    const float* prev_prob = (const float*)d_in[3];

    const int hist = in_sizes[2] / BEAM;   // 64
    const size_t OUT_KV = (size_t)LAY * BEAM * NH * SEQ * HD;  // 176,160,768

    float* out     = (float*)d_out;
    int*   beam_ws = (int*)d_ws;
    Partial* part  = (Partial*)((char*)d_ws + 64);

    pass_a<<<BEAM * NBLK, 256, 0, stream>>>(logits, part);
    pass_b<<<1, 64, 0, stream>>>(part, save_id, prev_prob, out + OUT_KV, beam_ws, hist);
    copy_kv<<<4096, 256, 0, stream>>>((const f32x4*)kv, beam_ws, (f32x4*)out);
}